// Round 4
// baseline (467.068 us; speedup 1.0000x reference)
//
#include <hip/hip_runtime.h>

#define NODE 8192
#define FEAT 64
#define OUTD 64
#define NCOL 256  // BATCH*OUTD

typedef float f32x4 __attribute__((ext_vector_type(4)));
typedef short s16x8 __attribute__((ext_vector_type(8)));
typedef short s16x4 __attribute__((ext_vector_type(4)));
typedef int   i32x4 __attribute__((ext_vector_type(4)));

__device__ __forceinline__ short f2bf(float f) {
    // round-to-nearest-even fp32 -> bf16 (finite inputs)
    unsigned u = __builtin_bit_cast(unsigned, f);
    u += 0x7FFFu + ((u >> 16) & 1u);
    return (short)(u >> 16);
}

__device__ __forceinline__ s16x8 pack8(const f32x4& a, const f32x4& b) {
    s16x8 r;
#pragma unroll
    for (int i = 0; i < 4; ++i) r[i] = f2bf(a[i]);
#pragma unroll
    for (int i = 0; i < 4; ++i) r[4 + i] = f2bf(b[i]);
    return r;
}

// async global->LDS DMA, 16B per lane, NO register destination (the R2/R3
// crash mechanism was "=v" asm loads; this builtin is the m97/m201-proven
// path).  LDS dest must be wave-uniform; global src is per-lane.
__device__ __forceinline__ void gl2lds16(const float* g, float* l) {
    __builtin_amdgcn_global_load_lds(
        (const __attribute__((address_space(1))) void*)g,
        (__attribute__((address_space(3))) void*)l, 16, 0, 0);
}

// ---------------------------------------------------------------------------
// k0: bias2[o] = b_out[o] + sum_f nl_b[f] * w_out[o,f]   (R1 bit-exact)
// ---------------------------------------------------------------------------
__global__ void bias2_kernel(const float* __restrict__ nl_b,
                             const float* __restrict__ w_out,
                             const float* __restrict__ b_out,
                             float* __restrict__ bias2) {
    __shared__ float part[4][64];
    const int o = threadIdx.x & 63;
    const int fc = threadIdx.x >> 6;
    float s = 0.f;
#pragma unroll
    for (int i = 0; i < 16; ++i) {
        int f = fc * 16 + i;
        s += nl_b[f] * w_out[o * FEAT + f];
    }
    part[fc][o] = s;
    __syncthreads();
    if (fc == 0)
        bias2[o] = b_out[o] + part[0][o] + part[1][o] + part[2][o] + part[3][o];
}

// ---------------------------------------------------------------------------
// k0b: out[b,i,o] = bias2[o]   (R1 bit-exact)
// ---------------------------------------------------------------------------
__global__ __launch_bounds__(256) void init_out_kernel(
    float* __restrict__ out, const float* __restrict__ bias2) {
    const int idx = (int)blockIdx.x * 256 + threadIdx.x;
    f32x4 bv = *(const f32x4*)(bias2 + ((idx & 15) << 2));
    *(f32x4*)(out + (size_t)idx * 4) = bv;
}

// ---------------------------------------------------------------------------
// k1: Ybf in gemm B-fragment swizzled order (R1 bit-exact, passed).
// ---------------------------------------------------------------------------
__global__ __launch_bounds__(256) void build_ybf_kernel(
    const float* __restrict__ x, const float* __restrict__ nl_w,
    const float* __restrict__ w_out, unsigned short* __restrict__ ybf) {
    __shared__ float xs[128 * 65];   // [jl][f], stride 65
    __shared__ float w2t[64 * 68];   // [f][o],  stride 68
    const int tid = threadIdx.x;
    const int b   = (int)blockIdx.x >> 6;
    const int j0  = ((int)blockIdx.x & 63) << 7;

    const f32x4* src = (const f32x4*)(x + ((size_t)b * NODE + j0) * FEAT);
#pragma unroll
    for (int it = 0; it < 8; ++it) {
        int i = tid + it * 256;
        f32x4 v = src[i];
        int jl = i >> 4, f0 = (i & 15) << 2;
        float* d = &xs[jl * 65 + f0];
        d[0] = v[0]; d[1] = v[1]; d[2] = v[2]; d[3] = v[3];
    }
#pragma unroll
    for (int it = 0; it < 16; ++it) {
        int i = tid + it * 256;
        int o = i >> 6, f = i & 63;
        w2t[f * 68 + o] = w_out[i] * (0.70710678118654752f * nl_w[f]);
    }
    __syncthreads();

    const int oq = tid & 15;
    const int J  = tid >> 4;
    const float* xr = &xs[(J * 8) * 65];
    const float* wr = &w2t[oq * 4];

    float acc[4][8];
#pragma unroll
    for (int i = 0; i < 4; ++i)
#pragma unroll
        for (int e = 0; e < 8; ++e) acc[i][e] = 0.f;

#pragma unroll 4
    for (int f = 0; f < 64; ++f) {
        f32x4 w4 = *(const f32x4*)(wr + f * 68);
        float xv[8];
#pragma unroll
        for (int e = 0; e < 8; ++e) xv[e] = xr[e * 65 + f];
#pragma unroll
        for (int i = 0; i < 4; ++i)
#pragma unroll
            for (int e = 0; e < 8; ++e) acc[i][e] += w4[i] * xv[e];
    }

    const int jn0 = j0 + J * 8;
    const int kb  = jn0 >> 5;
    const int q   = (jn0 >> 3) & 3;
    const int c16 = b * 4 + (oq >> 2);
    unsigned short* dst = ybf + ((size_t)(c16 * 256 + kb) * 512) +
                          q * 128 + ((oq & 3) * 4) * 8;
#pragma unroll
    for (int i = 0; i < 4; ++i) {
        s16x8 pv;
#pragma unroll
        for (int e = 0; e < 8; ++e) pv[e] = f2bf(acc[i][e]);
        *(s16x8*)(dst + i * 8) = pv;
    }
}

// ---------------------------------------------------------------------------
// k2: out += adj @ Y.  2048 blocks x 256 thr.
// R3 post-mortem: "=v" volatile-asm loads crashed the container twice ->
// abandoned.  This version gets the same explicit MLP via the m201-proven
// idiom: global_load_lds (no register dest) + counted asm vmcnt +
// sched_barrier(0) fences.  Wave-private 4-slot LDS rotation, NO barriers.
//  - A tile (32x32 fp32/wave/round) staged by 4 gload_lds (each: 64 lanes x
//    16B = 1KB linear LDS).  LDS layout XOR-swizzled byte^=(row&7)<<4 to
//    break the stride-128B bank conflict; applied by PRE-SWIZZLING the
//    global source address (rule #21): lane l of instr g fetches
//    row = row0+g*8+(l>>3), chunk (l&7)^(l>>3) -> 8-lane groups still cover
//    whole 128B lines (coalesced).
//  - Frag read: ds_read_b128 fp32 at r*128 + (chunk*16 ^ ((r&7)<<4)),
//    cvt->bf16 in-reg (pack8), 8 MFMA.  B: plain HIP loads, double-buffered
//    (compiler-tracked; its waits count our DMAs too -> only ever stricter).
//  - vmcnt ledger (gload_lds only): prologue fills slots 0-3 (16 in
//    flight); round t waits vmcnt(12) -> A(t) forced complete (load->use
//    >= 2 round-times ~ 1200cy > 900cy HBM), issues A(t+4) into freed slot.
//  - Decode unchanged (R1-verified): cg fastest co-XCD (adj fetched once),
//    ks co-XCD (L2-local atomics), rg=(w>>5)*8+xcd.
// ---------------------------------------------------------------------------
__global__ __launch_bounds__(256, 2) void gemm_adj_kernel(
    const float* __restrict__ adj, const unsigned short* __restrict__ ybf,
    float* __restrict__ out) {
    __shared__ __align__(16) float As[4][4][1024];  // [wave][slot][32x32 f32]

    const int tid  = threadIdx.x;
    const int lane = tid & 63;
    const int wv   = tid >> 6;
    const int bi   = (int)blockIdx.x;
    const int xcd  = bi & 7;
    const int w    = bi >> 3;             // 0..255
    const int cg   = w & 3;               // batch
    const int ks   = (w >> 2) & 7;        // K-eighth (1024)
    const int rg   = (w >> 5) * 8 + xcd;  // rowgroup of 128
    const int row0 = rg * 128 + wv * 32;
    const int t16  = lane & 15;
    const int quad = lane >> 4;

    // A staging source (pre-swizzled): instr g, this lane
    const float* aSrc[4];
#pragma unroll
    for (int g = 0; g < 4; ++g)
        aSrc[g] = adj + (size_t)(row0 + g * 8 + (lane >> 3)) * NODE +
                  ks * 1024 + 4 * ((lane & 7) ^ (lane >> 3));

    // A frag read float-indices (swizzled): (m,h) -> row m*16+t16, chunk quad*2+h
    int aIdx[2][2];
#pragma unroll
    for (int m = 0; m < 2; ++m)
#pragma unroll
        for (int h = 0; h < 2; ++h)
            aIdx[m][h] = (m * 16 + t16) * 32 +
                         (((quad * 2 + h) ^ (lane & 7)) << 2);

    // B fragment pointers (swizzled ybf, R1-verified): tile t at +t*512 ushort
    const unsigned short* bpB[4];
#pragma unroll
    for (int nt = 0; nt < 4; ++nt)
        bpB[nt] = ybf + ((size_t)((cg * 4 + nt) * 256 + ks * 32) * 512) + lane * 8;

    i32x4 BF[2][4];
    f32x4 acc[2][4];
#pragma unroll
    for (int mi = 0; mi < 2; ++mi)
#pragma unroll
        for (int nt = 0; nt < 4; ++nt) acc[mi][nt] = (f32x4){0.f, 0.f, 0.f, 0.f};

    // ---- prologue: fill all 4 slots (16 gload_lds in flight), B 2-deep ----
#pragma unroll
    for (int s = 0; s < 4; ++s)
#pragma unroll
        for (int g = 0; g < 4; ++g)
            gl2lds16(aSrc[g] + s * 32, &As[wv][s][g * 256]);
    __builtin_amdgcn_sched_barrier(0);
#pragma unroll
    for (int nt = 0; nt < 4; ++nt) BF[0][nt] = *(const i32x4*)bpB[nt];
#pragma unroll
    for (int nt = 0; nt < 4; ++nt) BF[1][nt] = *(const i32x4*)(bpB[nt] + 512);

#define ROUND(qv, PH, BP)                                                     \
    {                                                                         \
        asm volatile("s_waitcnt vmcnt(12)" ::: "memory");                     \
        __builtin_amdgcn_sched_barrier(0);                                    \
        const float* sb = &As[wv][PH][0];                                     \
        f32x4 a00 = *(const f32x4*)(sb + aIdx[0][0]);                         \
        f32x4 a01 = *(const f32x4*)(sb + aIdx[0][1]);                         \
        f32x4 a10 = *(const f32x4*)(sb + aIdx[1][0]);                         \
        f32x4 a11 = *(const f32x4*)(sb + aIdx[1][1]);                         \
        s16x8 af0 = pack8(a00, a01);                                          \
        s16x8 af1 = pack8(a10, a11);                                          \
        _Pragma("unroll") for (int nt = 0; nt < 4; ++nt) {                    \
            s16x8 bf = __builtin_bit_cast(s16x8, BF[BP][nt]);                 \
            acc[0][nt] = __builtin_amdgcn_mfma_f32_16x16x32_bf16(             \
                af0, bf, acc[0][nt], 0, 0, 0);                                \
            acc[1][nt] = __builtin_amdgcn_mfma_f32_16x16x32_bf16(             \
                af1, bf, acc[1][nt], 0, 0, 0);                                \
        }                                                                     \
        {                                                                     \
            const int tB = ((qv) + 2) & 31;                                   \
            _Pragma("unroll") for (int nt = 0; nt < 4; ++nt)                  \
                BF[BP][nt] = *(const i32x4*)(bpB[nt] + (size_t)tB * 512);     \
        }                                                                     \
        __builtin_amdgcn_sched_barrier(0);                                    \
        {                                                                     \
            const int tA = ((qv) + 4) & 31;                                   \
            _Pragma("unroll") for (int g = 0; g < 4; ++g)                     \
                gl2lds16(aSrc[g] + tA * 32, &As[wv][PH][g * 256]);            \
        }                                                                     \
        __builtin_amdgcn_sched_barrier(0);                                    \
    }

#pragma unroll 1
    for (int q = 0; q < 32; q += 4) {
        ROUND(q + 0, 0, 0)
        ROUND(q + 1, 1, 1)
        ROUND(q + 2, 2, 0)
        ROUND(q + 3, 3, 1)
    }
#undef ROUND

    // drain outstanding DMA before the atomic epilogue
    asm volatile("s_waitcnt vmcnt(0)" ::: "memory");
    __builtin_amdgcn_sched_barrier(0);

    // ---- epilogue: accumulate into pre-biased out (ks-sharers co-XCD) ----
#pragma unroll
    for (int mi = 0; mi < 2; ++mi) {
        const int i0 = row0 + mi * 16 + quad * 4;
#pragma unroll
        for (int nt = 0; nt < 4; ++nt) {
            float* op = out + ((size_t)cg * NODE + i0) * OUTD + nt * 16 + t16;
#pragma unroll
            for (int rr = 0; rr < 4; ++rr)
                atomicAdd(op + (size_t)rr * OUTD, acc[mi][nt][rr]);
        }
    }
}

// ---------------------------------------------------------------------------
extern "C" void kernel_launch(void* const* d_in, const int* in_sizes, int n_in,
                              void* d_out, int out_size, void* d_ws, size_t ws_size,
                              hipStream_t stream) {
    const float* x     = (const float*)d_in[0];
    const float* adj   = (const float*)d_in[1];
    const float* nl_w  = (const float*)d_in[2];
    const float* nl_b  = (const float*)d_in[3];
    const float* w_out = (const float*)d_in[4];
    const float* b_out = (const float*)d_in[5];
    float* out = (float*)d_out;

    unsigned short* ybf = (unsigned short*)d_ws;                      // 4 MB
    float* bias2 = (float*)((char*)d_ws + (size_t)NCOL * NODE * 2);   // 64 fp32

    bias2_kernel<<<1, 256, 0, stream>>>(nl_b, w_out, b_out, bias2);
    init_out_kernel<<<2048, 256, 0, stream>>>(out, bias2);
    build_ybf_kernel<<<256, 256, 0, stream>>>(x, nl_w, w_out, ybf);
    gemm_adj_kernel<<<2048, 256, 0, stream>>>(adj, ybf, out);
}

// Round 6
// 450.201 us; speedup vs baseline: 1.0375x; 1.0375x over previous
//
#include <hip/hip_runtime.h>

#define NODE 8192
#define FEAT 64
#define OUTD 64
#define NCOL 256  // BATCH*OUTD

typedef float f32x4 __attribute__((ext_vector_type(4)));
typedef short s16x8 __attribute__((ext_vector_type(8)));
typedef short s16x4 __attribute__((ext_vector_type(4)));
typedef int   i32x4 __attribute__((ext_vector_type(4)));

__device__ __forceinline__ short f2bf(float f) {
    // round-to-nearest-even fp32 -> bf16 (finite inputs)
    unsigned u = __builtin_bit_cast(unsigned, f);
    u += 0x7FFFu + ((u >> 16) & 1u);
    return (short)(u >> 16);
}

__device__ __forceinline__ s16x8 pack8(const f32x4& a, const f32x4& b) {
    s16x8 r;
#pragma unroll
    for (int i = 0; i < 4; ++i) r[i] = f2bf(a[i]);
#pragma unroll
    for (int i = 0; i < 4; ++i) r[4 + i] = f2bf(b[i]);
    return r;
}

// async global->LDS DMA, 16B per lane, NO register destination (R2/R3 crash
// mechanism was "=v" asm loads; this builtin is the m97/m201-proven path).
__device__ __forceinline__ void gl2lds16(const float* g, float* l) {
    __builtin_amdgcn_global_load_lds(
        (const __attribute__((address_space(1))) void*)g,
        (__attribute__((address_space(3))) void*)l, 16, 0, 0);
}

// ---------------------------------------------------------------------------
// k0: bias2[o] = b_out[o] + sum_f nl_b[f] * w_out[o,f]   (R1 bit-exact)
// ---------------------------------------------------------------------------
__global__ void bias2_kernel(const float* __restrict__ nl_b,
                             const float* __restrict__ w_out,
                             const float* __restrict__ b_out,
                             float* __restrict__ bias2) {
    __shared__ float part[4][64];
    const int o = threadIdx.x & 63;
    const int fc = threadIdx.x >> 6;
    float s = 0.f;
#pragma unroll
    for (int i = 0; i < 16; ++i) {
        int f = fc * 16 + i;
        s += nl_b[f] * w_out[o * FEAT + f];
    }
    part[fc][o] = s;
    __syncthreads();
    if (fc == 0)
        bias2[o] = b_out[o] + part[0][o] + part[1][o] + part[2][o] + part[3][o];
}

// ---------------------------------------------------------------------------
// k1: Ybf in gemm B-fragment swizzled order (R1 bit-exact, passed).
// ---------------------------------------------------------------------------
__global__ __launch_bounds__(256) void build_ybf_kernel(
    const float* __restrict__ x, const float* __restrict__ nl_w,
    const float* __restrict__ w_out, unsigned short* __restrict__ ybf) {
    __shared__ float xs[128 * 65];   // [jl][f], stride 65
    __shared__ float w2t[64 * 68];   // [f][o],  stride 68
    const int tid = threadIdx.x;
    const int b   = (int)blockIdx.x >> 6;
    const int j0  = ((int)blockIdx.x & 63) << 7;

    const f32x4* src = (const f32x4*)(x + ((size_t)b * NODE + j0) * FEAT);
#pragma unroll
    for (int it = 0; it < 8; ++it) {
        int i = tid + it * 256;
        f32x4 v = src[i];
        int jl = i >> 4, f0 = (i & 15) << 2;
        float* d = &xs[jl * 65 + f0];
        d[0] = v[0]; d[1] = v[1]; d[2] = v[2]; d[3] = v[3];
    }
#pragma unroll
    for (int it = 0; it < 16; ++it) {
        int i = tid + it * 256;
        int o = i >> 6, f = i & 63;
        w2t[f * 68 + o] = w_out[i] * (0.70710678118654752f * nl_w[f]);
    }
    __syncthreads();

    const int oq = tid & 15;
    const int J  = tid >> 4;
    const float* xr = &xs[(J * 8) * 65];
    const float* wr = &w2t[oq * 4];

    float acc[4][8];
#pragma unroll
    for (int i = 0; i < 4; ++i)
#pragma unroll
        for (int e = 0; e < 8; ++e) acc[i][e] = 0.f;

#pragma unroll 4
    for (int f = 0; f < 64; ++f) {
        f32x4 w4 = *(const f32x4*)(wr + f * 68);
        float xv[8];
#pragma unroll
        for (int e = 0; e < 8; ++e) xv[e] = xr[e * 65 + f];
#pragma unroll
        for (int i = 0; i < 4; ++i)
#pragma unroll
            for (int e = 0; e < 8; ++e) acc[i][e] += w4[i] * xv[e];
    }

    const int jn0 = j0 + J * 8;
    const int kb  = jn0 >> 5;
    const int q   = (jn0 >> 3) & 3;
    const int c16 = b * 4 + (oq >> 2);
    unsigned short* dst = ybf + ((size_t)(c16 * 256 + kb) * 512) +
                          q * 128 + ((oq & 3) * 4) * 8;
#pragma unroll
    for (int i = 0; i < 4; ++i) {
        s16x8 pv;
#pragma unroll
        for (int e = 0; e < 8; ++e) pv[e] = f2bf(acc[i][e]);
        *(s16x8*)(dst + i * 8) = pv;
    }
}

// ---------------------------------------------------------------------------
// k2: out = bias2 + adj @ Y.  1024 blocks x 256 thr, ZERO ATOMICS.
// R5 post-mortem (absmax 0.276): LDS-reuse RACE.  pl[wv*2048] for waves 2,3
// lives in As[1][...] = wave 1's STAGING buffer; the K-loop is barrier-free
// so a fast wave's partial-store collided with a slow wave's in-flight DMA.
// Fix: __syncthreads() AFTER each wave's vmcnt(0) drain and BEFORE the
// partial writes -> post-barrier the staging LDS is provably dead (each
// wave drained its own DMA queue pre-barrier).  Everything else identical
// to R5: wave wv owns K-quarter wv*2048; 4-slot DMA rotation; vmcnt(12)
// ledger (A load->use >= 2 round-times); swizzled LDS (rule #21); 64
// rounds; epilogue 4-way LDS reduce + bias2 + coalesced f32x4 stores.
// Decode: xcd=bi&7, w=bi>>3: cg=w&3, rg=(w>>2)*8+xcd -> adj fetched ~once.
// ---------------------------------------------------------------------------
__global__ __launch_bounds__(256, 2) void gemm_adj_kernel(
    const float* __restrict__ adj, const unsigned short* __restrict__ ybf,
    const float* __restrict__ bias2, float* __restrict__ out) {
    __shared__ __align__(16) float As[4][4][1024];  // [wave][slot][32x32 f32]

    const int tid  = threadIdx.x;
    const int lane = tid & 63;
    const int wv   = tid >> 6;            // K-quarter owner
    const int bi   = (int)blockIdx.x;
    const int xcd  = bi & 7;
    const int w    = bi >> 3;             // 0..127
    const int cg   = w & 3;               // batch
    const int rg   = (w >> 2) * 8 + xcd;  // 0..255, rowgroup of 32
    const int row0 = rg * 32;
    const int t16  = lane & 15;
    const int quad = lane >> 4;

    // A staging source (pre-swizzled, rule #21): instr g, this lane
    const float* aSrc[4];
#pragma unroll
    for (int g = 0; g < 4; ++g)
        aSrc[g] = adj + (size_t)(row0 + g * 8 + (lane >> 3)) * NODE +
                  wv * 2048 + 4 * ((lane & 7) ^ (lane >> 3));

    // A frag read float-indices (swizzled): (m,h) -> row m*16+t16, chunk quad*2+h
    int aIdx[2][2];
#pragma unroll
    for (int m = 0; m < 2; ++m)
#pragma unroll
        for (int h = 0; h < 2; ++h)
            aIdx[m][h] = (m * 16 + t16) * 32 +
                         (((quad * 2 + h) ^ (lane & 7)) << 2);

    // B fragment pointers (swizzled ybf, R1-verified): tile t at +t*512 ushort
    const unsigned short* bpB[4];
#pragma unroll
    for (int nt = 0; nt < 4; ++nt)
        bpB[nt] = ybf + ((size_t)((cg * 4 + nt) * 256 + wv * 64) * 512) + lane * 8;

    i32x4 BF[2][4];
    f32x4 acc[2][4];
#pragma unroll
    for (int mi = 0; mi < 2; ++mi)
#pragma unroll
        for (int nt = 0; nt < 4; ++nt) acc[mi][nt] = (f32x4){0.f, 0.f, 0.f, 0.f};

    // ---- prologue: fill all 4 slots (16 gload_lds in flight), B 2-deep ----
#pragma unroll
    for (int s = 0; s < 4; ++s)
#pragma unroll
        for (int g = 0; g < 4; ++g)
            gl2lds16(aSrc[g] + s * 32, &As[wv][s][g * 256]);
    __builtin_amdgcn_sched_barrier(0);
#pragma unroll
    for (int nt = 0; nt < 4; ++nt) BF[0][nt] = *(const i32x4*)bpB[nt];
#pragma unroll
    for (int nt = 0; nt < 4; ++nt) BF[1][nt] = *(const i32x4*)(bpB[nt] + 512);

#define ROUND(qv, PH, BP)                                                     \
    {                                                                         \
        asm volatile("s_waitcnt vmcnt(12)" ::: "memory");                     \
        __builtin_amdgcn_sched_barrier(0);                                    \
        const float* sb = &As[wv][PH][0];                                     \
        f32x4 a00 = *(const f32x4*)(sb + aIdx[0][0]);                         \
        f32x4 a01 = *(const f32x4*)(sb + aIdx[0][1]);                         \
        f32x4 a10 = *(const f32x4*)(sb + aIdx[1][0]);                         \
        f32x4 a11 = *(const f32x4*)(sb + aIdx[1][1]);                         \
        s16x8 af0 = pack8(a00, a01);                                          \
        s16x8 af1 = pack8(a10, a11);                                          \
        _Pragma("unroll") for (int nt = 0; nt < 4; ++nt) {                    \
            s16x8 bf = __builtin_bit_cast(s16x8, BF[BP][nt]);                 \
            acc[0][nt] = __builtin_amdgcn_mfma_f32_16x16x32_bf16(             \
                af0, bf, acc[0][nt], 0, 0, 0);                                \
            acc[1][nt] = __builtin_amdgcn_mfma_f32_16x16x32_bf16(             \
                af1, bf, acc[1][nt], 0, 0, 0);                                \
        }                                                                     \
        {                                                                     \
            const int tB = ((qv) + 2) & 63;                                   \
            _Pragma("unroll") for (int nt = 0; nt < 4; ++nt)                  \
                BF[BP][nt] = *(const i32x4*)(bpB[nt] + (size_t)tB * 512);     \
        }                                                                     \
        __builtin_amdgcn_sched_barrier(0);                                    \
        {                                                                     \
            const int tA = ((qv) + 4) & 63;                                   \
            _Pragma("unroll") for (int g = 0; g < 4; ++g)                     \
                gl2lds16(aSrc[g] + tA * 32, &As[wv][PH][g * 256]);            \
        }                                                                     \
        __builtin_amdgcn_sched_barrier(0);                                    \
    }

#pragma unroll 1
    for (int q = 0; q < 64; q += 4) {
        ROUND(q + 0, 0, 0)
        ROUND(q + 1, 1, 1)
        ROUND(q + 2, 2, 0)
        ROUND(q + 3, 3, 1)
    }
#undef ROUND

    // drain THIS wave's outstanding DMA, then barrier: after it, no DMA is
    // in flight block-wide and the staging LDS is dead -> safe to reuse.
    asm volatile("s_waitcnt vmcnt(0)" ::: "memory");
    __builtin_amdgcn_sched_barrier(0);
    __syncthreads();   // <-- R5 race fix

    // ---- epilogue: per-wave partials into (dead) staging LDS, reduce ----
    float* pl = &As[0][0][0];  // 16384 floats; partials need 4*2048
#pragma unroll
    for (int mi = 0; mi < 2; ++mi)
#pragma unroll
        for (int nt = 0; nt < 4; ++nt)
#pragma unroll
            for (int rr = 0; rr < 4; ++rr)
                pl[wv * 2048 + (mi * 16 + quad * 4 + rr) * 64 + nt * 16 + t16] =
                    acc[mi][nt][rr];
    __syncthreads();

#pragma unroll
    for (int cc = 0; cc < 2; ++cc) {
        const int cid = tid * 2 + cc;      // 0..511
        const int row = cid >> 4;          // 0..31
        const int c4  = (cid & 15) << 2;   // 0..60
        f32x4 s = *(const f32x4*)(pl + row * 64 + c4);
#pragma unroll
        for (int w2 = 1; w2 < 4; ++w2) {
            f32x4 p = *(const f32x4*)(pl + w2 * 2048 + row * 64 + c4);
            s[0] += p[0]; s[1] += p[1]; s[2] += p[2]; s[3] += p[3];
        }
        f32x4 bb = *(const f32x4*)(bias2 + c4);
        s[0] += bb[0]; s[1] += bb[1]; s[2] += bb[2]; s[3] += bb[3];
        *(f32x4*)(out + ((size_t)cg * NODE + row0 + row) * OUTD + c4) = s;
    }
}

// ---------------------------------------------------------------------------
extern "C" void kernel_launch(void* const* d_in, const int* in_sizes, int n_in,
                              void* d_out, int out_size, void* d_ws, size_t ws_size,
                              hipStream_t stream) {
    const float* x     = (const float*)d_in[0];
    const float* adj   = (const float*)d_in[1];
    const float* nl_w  = (const float*)d_in[2];
    const float* nl_b  = (const float*)d_in[3];
    const float* w_out = (const float*)d_in[4];
    const float* b_out = (const float*)d_in[5];
    float* out = (float*)d_out;

    unsigned short* ybf = (unsigned short*)d_ws;                      // 4 MB
    float* bias2 = (float*)((char*)d_ws + (size_t)NCOL * NODE * 2);   // 64 fp32

    bias2_kernel<<<1, 256, 0, stream>>>(nl_b, w_out, b_out, bias2);
    build_ybf_kernel<<<256, 256, 0, stream>>>(x, nl_w, w_out, ybf);
    gemm_adj_kernel<<<1024, 256, 0, stream>>>(adj, ybf, bias2, out);
}